// Round 1
// baseline (13877.214 us; speedup 1.0000x reference)
//
#include <hip/hip_runtime.h>
#include <hip/hip_bf16.h>
#include <math.h>

#define BB 16
#define TT 256
#define DD 512
#define EE 512
#define VV 32000
#define G4 2048   // 4*D

typedef __attribute__((ext_vector_type(4))) float f32x4;
typedef __attribute__((ext_vector_type(8))) short bf16x8;

__device__ __forceinline__ unsigned short f2bf(float x) {
    unsigned u = __float_as_uint(x);
    unsigned r = (u + 0x7FFFu + ((u >> 16) & 1u)) >> 16;
    return (unsigned short)r;
}

__device__ __forceinline__ float sigmoidf_(float x) { return 1.0f / (1.0f + expf(-x)); }

// ---------------- embedding gather -> bf16 (padding_idx=0 -> zero row) ----------------
__global__ __launch_bounds__(256) void k_gather(const int* __restrict__ tok,
        const float* __restrict__ embed, unsigned short* __restrict__ Xb) {
    int m = blockIdx.x;              // flat b*T + t  (matches [B,T] layout)
    int tk = tok[m];
    const float* src = embed + (size_t)tk * DD;
    int i = threadIdx.x * 2;
    float vx = 0.f, vy = 0.f;
    if (tk != 0) { float2 v = *(const float2*)&src[i]; vx = v.x; vy = v.y; }
    ushort2 o; o.x = f2bf(vx); o.y = f2bf(vy);
    *(ushort2*)&Xb[(size_t)m * DD + i] = o;
}

// ---------------- generic fp32 -> bf16 convert (contiguous) ----------------
__global__ __launch_bounds__(256) void k_cvt(const float* __restrict__ in,
        unsigned short* __restrict__ out, int n4) {
    int i = blockIdx.x * 256 + threadIdx.x;
    if (i >= n4) return;
    float4 v = ((const float4*)in)[i];
    ushort4 o; o.x = f2bf(v.x); o.y = f2bf(v.y); o.z = f2bf(v.z); o.w = f2bf(v.w);
    ((ushort4*)out)[i] = o;
}

// ---------------- W_ih0[:, 0:512] -> packed bf16 [2048,512] ----------------
__global__ __launch_bounds__(256) void k_cvt_wih0x(const float* __restrict__ Wih0,
        unsigned short* __restrict__ out) {
    int i = blockIdx.x * 256 + threadIdx.x;   // quad index, total 2048*128
    int j = i >> 7;
    int k4 = (i & 127) << 2;
    float4 v = *(const float4*)&Wih0[(size_t)j * (EE + DD) + k4];
    ushort4 o; o.x = f2bf(v.x); o.y = f2bf(v.y); o.z = f2bf(v.z); o.w = f2bf(v.w);
    *(ushort4*)&out[(size_t)j * DD + k4] = o;
}

// ---------------- enc_term[b,j] = b_ih0[j]+b_hh0[j] + enc[b,:] . W_ih0[j, 512:1024] ----------------
__global__ __launch_bounds__(256) void k_encterm(const float* __restrict__ enc,
        const float* __restrict__ Wih0, const float* __restrict__ bih0,
        const float* __restrict__ bhh0, float* __restrict__ et) {
    int b = blockIdx.x >> 3, jc = blockIdx.x & 7;
    int tid = threadIdx.x, lane = tid & 63, w = tid >> 6;
    __shared__ float es[EE];
    if (tid < EE / 4) *(float4*)&es[tid * 4] = *(const float4*)&enc[b * EE + tid * 4];
    __syncthreads();
    float4 e0 = *(const float4*)&es[lane * 4];
    float4 e1 = *(const float4*)&es[256 + lane * 4];
    for (int o = 0; o < 64; ++o) {
        int j = jc * 256 + w * 64 + o;
        const float4* Wr = (const float4*)&Wih0[(size_t)j * (EE + DD) + DD];
        float4 w0 = Wr[lane], w1 = Wr[64 + lane];
        float s = w0.x*e0.x + w0.y*e0.y + w0.z*e0.z + w0.w*e0.w
                + w1.x*e1.x + w1.y*e1.y + w1.z*e1.z + w1.w*e1.w;
        #pragma unroll
        for (int off = 32; off; off >>= 1) s += __shfl_xor(s, off);
        if (lane == 0) et[b * G4 + j] = s + bih0[j] + bhh0[j];
    }
}

// ---------------- bf16 MFMA GEMM, C[M,N] = A[M,K] @ B[N,K]^T  (m97 structure) ----------------
// EPI 0: C = acc + extra[(row>>8)*2048 + col]   (Gx epilogue: enc_term per b)
// EPI 1: C = acc + extra[col]                   (output epilogue: b_out)
template<int EPI>
__global__ __launch_bounds__(256) void k_gemm_bt(
        const unsigned short* __restrict__ A, const unsigned short* __restrict__ Bm,
        float* __restrict__ C, const float* __restrict__ extra,
        int M, int N, int K) {
    __shared__ __align__(16) unsigned short Alds[128 * 32];
    __shared__ __align__(16) unsigned short Blds[128 * 32];
    int tid = threadIdx.x, lane = tid & 63, w = tid >> 6;
    int wr = w >> 1, wc = w & 1;
    int m0 = blockIdx.x * 128, n0 = blockIdx.y * 128;
    f32x4 acc[4][4];
    #pragma unroll
    for (int i = 0; i < 4; i++)
        #pragma unroll
        for (int j = 0; j < 4; j++) acc[i][j] = (f32x4)0.f;

    const char* Abase = (const char*)A;
    const char* Bbase = (const char*)Bm;
    for (int ks = 0; ks < K; ks += 32) {
        #pragma unroll
        for (int c = 0; c < 2; ++c) {
            int f = (tid + c * 256) * 16;      // byte offset within 8KB tile
            int row = f >> 6;                  // 64 B per row (32 bf16)
            int inb = f & 63;
            const char* gA = Abase + (((size_t)(m0 + row) * K + ks) * 2 + inb);
            __builtin_amdgcn_global_load_lds(
                (const __attribute__((address_space(1))) void*)gA,
                (__attribute__((address_space(3))) void*)((char*)Alds + f), 16, 0, 0);
            const char* gB = Bbase + (((size_t)(n0 + row) * K + ks) * 2 + inb);
            __builtin_amdgcn_global_load_lds(
                (const __attribute__((address_space(1))) void*)gB,
                (__attribute__((address_space(3))) void*)((char*)Blds + f), 16, 0, 0);
        }
        __syncthreads();
        bf16x8 af[4], bfr[4];
        int r = lane & 15, ko = (lane >> 4) * 8;
        #pragma unroll
        for (int mi = 0; mi < 4; ++mi)
            af[mi] = *(const bf16x8*)&Alds[(wr * 64 + mi * 16 + r) * 32 + ko];
        #pragma unroll
        for (int ni = 0; ni < 4; ++ni)
            bfr[ni] = *(const bf16x8*)&Blds[(wc * 64 + ni * 16 + r) * 32 + ko];
        #pragma unroll
        for (int mi = 0; mi < 4; ++mi)
            #pragma unroll
            for (int ni = 0; ni < 4; ++ni)
                acc[mi][ni] = __builtin_amdgcn_mfma_f32_16x16x32_bf16(af[mi], bfr[ni], acc[mi][ni], 0, 0, 0);
        __syncthreads();
    }
    int cr = (lane >> 4) * 4, cc = lane & 15;
    #pragma unroll
    for (int mi = 0; mi < 4; ++mi) {
        #pragma unroll
        for (int ni = 0; ni < 4; ++ni) {
            int col = n0 + wc * 64 + ni * 16 + cc;
            #pragma unroll
            for (int rr = 0; rr < 4; ++rr) {
                int rowg = m0 + wr * 64 + mi * 16 + cr + rr;
                float v = acc[mi][ni][rr];
                if (EPI == 0) v += extra[(rowg >> 8) * G4 + col];
                else          v += extra[col];
                C[(size_t)rowg * N + col] = v;
            }
        }
    }
}

// ---------------- LSTM layer 0, one step: gates = Gx[t] + h0 @ W_hh0^T ----------------
__global__ __launch_bounds__(256) void k_lstm0(
        const float* __restrict__ Gx, const float* __restrict__ Whh0,
        const float* __restrict__ h_in, const float* __restrict__ c_in,
        float* __restrict__ h_out, float* __restrict__ c_out, int t) {
    int b = blockIdx.x >> 3, ch = blockIdx.x & 7;
    int d0 = ch * 64;
    int tid = threadIdx.x, lane = tid & 63, w = tid >> 6;   // wave = gate (i,f,g,o)
    __shared__ float hs[DD];
    __shared__ float gl[4][64];
    if (tid < DD / 4) *(float4*)&hs[tid * 4] = *(const float4*)&h_in[b * DD + tid * 4];
    __syncthreads();
    float4 h0v = *(const float4*)&hs[lane * 4];
    float4 h1v = *(const float4*)&hs[256 + lane * 4];
    const float* grow = Gx + (size_t)(b * TT + t) * G4;
    for (int o = 0; o < 64; ++o) {
        int j = w * 512 + d0 + o;
        const float4* Wr = (const float4*)&Whh0[(size_t)j * DD];
        float4 w0 = Wr[lane], w1 = Wr[64 + lane];
        float s = w0.x*h0v.x + w0.y*h0v.y + w0.z*h0v.z + w0.w*h0v.w
                + w1.x*h1v.x + w1.y*h1v.y + w1.z*h1v.z + w1.w*h1v.w;
        #pragma unroll
        for (int off = 32; off; off >>= 1) s += __shfl_xor(s, off);
        if (lane == 0) gl[w][o] = s + grow[j];
    }
    __syncthreads();
    if (tid < 64) {
        int d = d0 + tid;
        float gi = gl[0][tid], gf = gl[1][tid], gg = gl[2][tid], go = gl[3][tid];
        float c = c_in[b * DD + d];
        float cn = sigmoidf_(gf) * c + sigmoidf_(gi) * tanhf(gg);
        float hn = sigmoidf_(go) * tanhf(cn);
        c_out[b * DD + d] = cn;
        h_out[b * DD + d] = hn;
    }
}

// ---------------- LSTM layer 1, one step ----------------
__global__ __launch_bounds__(256) void k_lstm1(
        const float* __restrict__ Wih1, const float* __restrict__ Whh1,
        const float* __restrict__ bih1, const float* __restrict__ bhh1,
        const float* __restrict__ h0new, const float* __restrict__ h_in,
        const float* __restrict__ c_in, float* __restrict__ h_out,
        float* __restrict__ c_out, unsigned short* __restrict__ outsb, int t) {
    int b = blockIdx.x >> 3, ch = blockIdx.x & 7;
    int d0 = ch * 64;
    int tid = threadIdx.x, lane = tid & 63, w = tid >> 6;
    __shared__ float xs[DD], hs[DD];
    __shared__ float gl[4][64];
    if (tid < 128) *(float4*)&xs[tid * 4] = *(const float4*)&h0new[b * DD + tid * 4];
    else { int q = tid - 128; *(float4*)&hs[q * 4] = *(const float4*)&h_in[b * DD + q * 4]; }
    __syncthreads();
    float4 x0 = *(const float4*)&xs[lane * 4], x1 = *(const float4*)&xs[256 + lane * 4];
    float4 h0v = *(const float4*)&hs[lane * 4], h1v = *(const float4*)&hs[256 + lane * 4];
    for (int o = 0; o < 64; ++o) {
        int j = w * 512 + d0 + o;
        const float4* Ar = (const float4*)&Wih1[(size_t)j * DD];
        const float4* Br = (const float4*)&Whh1[(size_t)j * DD];
        float4 a0 = Ar[lane], a1 = Ar[64 + lane];
        float4 b0 = Br[lane], b1 = Br[64 + lane];
        float s = a0.x*x0.x + a0.y*x0.y + a0.z*x0.z + a0.w*x0.w
                + a1.x*x1.x + a1.y*x1.y + a1.z*x1.z + a1.w*x1.w
                + b0.x*h0v.x + b0.y*h0v.y + b0.z*h0v.z + b0.w*h0v.w
                + b1.x*h1v.x + b1.y*h1v.y + b1.z*h1v.z + b1.w*h1v.w;
        #pragma unroll
        for (int off = 32; off; off >>= 1) s += __shfl_xor(s, off);
        if (lane == 0) gl[w][o] = s + bih1[j] + bhh1[j];
    }
    __syncthreads();
    if (tid < 64) {
        int d = d0 + tid;
        float gi = gl[0][tid], gf = gl[1][tid], gg = gl[2][tid], go = gl[3][tid];
        float c = c_in[b * DD + d];
        float cn = sigmoidf_(gf) * c + sigmoidf_(gi) * tanhf(gg);
        float hn = sigmoidf_(go) * tanhf(cn);
        c_out[b * DD + d] = cn;
        h_out[b * DD + d] = hn;
        outsb[(size_t)(b * TT + t) * DD + d] = f2bf(hn);
    }
}

extern "C" void kernel_launch(void* const* d_in, const int* in_sizes, int n_in,
                              void* d_out, int out_size, void* d_ws, size_t ws_size,
                              hipStream_t stream) {
    const int*   tok   = (const int*)  d_in[0];
    const float* enc   = (const float*)d_in[1];
    const float* embed = (const float*)d_in[2];
    const float* Wih0  = (const float*)d_in[3];
    const float* Whh0  = (const float*)d_in[4];
    const float* bih0  = (const float*)d_in[5];
    const float* bhh0  = (const float*)d_in[6];
    const float* Wih1  = (const float*)d_in[7];
    const float* Whh1  = (const float*)d_in[8];
    const float* bih1  = (const float*)d_in[9];
    const float* bhh1  = (const float*)d_in[10];
    const float* Wout  = (const float*)d_in[11];
    const float* bout  = (const float*)d_in[12];
    float* out = (float*)d_out;

    char* ws = (char*)d_ws;
    size_t off = 0;
    auto alloc = [&](size_t bytes) -> char* {
        char* p = ws + off; off += (bytes + 255) & ~(size_t)255; return p;
    };
    float*          state  = (float*)alloc((size_t)8 * BB * DD * sizeof(float));
    unsigned short* Xb     = (unsigned short*)alloc((size_t)BB * TT * DD * 2);
    unsigned short* Wih0xb = (unsigned short*)alloc((size_t)G4 * DD * 2);
    unsigned short* Woutb  = (unsigned short*)alloc((size_t)VV * DD * 2);
    float*          et     = (float*)alloc((size_t)BB * G4 * sizeof(float));
    float*          Gx     = (float*)alloc((size_t)BB * TT * G4 * sizeof(float));
    unsigned short* outsb  = (unsigned short*)alloc((size_t)BB * TT * DD * 2);

    hipMemsetAsync(state, 0, (size_t)8 * BB * DD * sizeof(float), stream);
    k_gather<<<BB * TT, 256, 0, stream>>>(tok, embed, Xb);
    k_cvt<<<(VV * DD / 4 + 255) / 256, 256, 0, stream>>>(Wout, Woutb, VV * DD / 4);
    k_cvt_wih0x<<<(G4 * DD / 4) / 256, 256, 0, stream>>>(Wih0, Wih0xb);
    k_encterm<<<BB * 8, 256, 0, stream>>>(enc, Wih0, bih0, bhh0, et);

    dim3 g1(BB * TT / 128, G4 / 128);
    k_gemm_bt<0><<<g1, 256, 0, stream>>>(Xb, Wih0xb, Gx, et, BB * TT, G4, DD);

    float* h0[2] = { state + 0 * BB * DD, state + 4 * BB * DD };
    float* c0[2] = { state + 1 * BB * DD, state + 5 * BB * DD };
    float* h1[2] = { state + 2 * BB * DD, state + 6 * BB * DD };
    float* c1[2] = { state + 3 * BB * DD, state + 7 * BB * DD };
    for (int t = 0; t < TT; ++t) {
        int p = t & 1, q = p ^ 1;
        k_lstm0<<<BB * 8, 256, 0, stream>>>(Gx, Whh0, h0[p], c0[p], h0[q], c0[q], t);
        k_lstm1<<<BB * 8, 256, 0, stream>>>(Wih1, Whh1, bih1, bhh1,
                                            h0[q], h1[p], c1[p], h1[q], c1[q], outsb, t);
    }

    dim3 g2(BB * TT / 128, VV / 128);
    k_gemm_bt<1><<<g2, 256, 0, stream>>>(outsb, Woutb, out, bout, BB * TT, VV, DD);
}

// Round 2
// 3121.233 us; speedup vs baseline: 4.4461x; 4.4461x over previous
//
#include <hip/hip_runtime.h>
#include <hip/hip_bf16.h>
#include <math.h>

#define BB 16
#define TT 256
#define DD 512
#define EE 512
#define VV 32000
#define G4 2048   // 4*D

typedef __attribute__((ext_vector_type(4))) float f32x4;
typedef __attribute__((ext_vector_type(8))) short bf16x8;

__device__ __forceinline__ unsigned short f2bf(float x) {
    unsigned u = __float_as_uint(x);
    unsigned r = (u + 0x7FFFu + ((u >> 16) & 1u)) >> 16;
    return (unsigned short)r;
}

__device__ __forceinline__ float sigmoidf_(float x) { return 1.0f / (1.0f + expf(-x)); }

// ---------------- embedding gather -> bf16 (padding_idx=0 -> zero row) ----------------
__global__ __launch_bounds__(256) void k_gather(const int* __restrict__ tok,
        const float* __restrict__ embed, unsigned short* __restrict__ Xb) {
    int m = blockIdx.x;              // flat b*T + t  (matches [B,T] layout)
    int tk = tok[m];
    const float* src = embed + (size_t)tk * DD;
    int i = threadIdx.x * 2;
    float vx = 0.f, vy = 0.f;
    if (tk != 0) { float2 v = *(const float2*)&src[i]; vx = v.x; vy = v.y; }
    ushort2 o; o.x = f2bf(vx); o.y = f2bf(vy);
    *(ushort2*)&Xb[(size_t)m * DD + i] = o;
}

// ---------------- generic fp32 -> bf16 convert (contiguous) ----------------
__global__ __launch_bounds__(256) void k_cvt(const float* __restrict__ in,
        unsigned short* __restrict__ out, int n4) {
    int i = blockIdx.x * 256 + threadIdx.x;
    if (i >= n4) return;
    float4 v = ((const float4*)in)[i];
    ushort4 o; o.x = f2bf(v.x); o.y = f2bf(v.y); o.z = f2bf(v.z); o.w = f2bf(v.w);
    ((ushort4*)out)[i] = o;
}

// ---------------- W_ih0[:, 0:512] -> packed bf16 [2048,512] ----------------
__global__ __launch_bounds__(256) void k_cvt_wih0x(const float* __restrict__ Wih0,
        unsigned short* __restrict__ out) {
    int i = blockIdx.x * 256 + threadIdx.x;   // quad index, total 2048*128
    int j = i >> 7;
    int k4 = (i & 127) << 2;
    float4 v = *(const float4*)&Wih0[(size_t)j * (EE + DD) + k4];
    ushort4 o; o.x = f2bf(v.x); o.y = f2bf(v.y); o.z = f2bf(v.z); o.w = f2bf(v.w);
    *(ushort4*)&out[(size_t)j * DD + k4] = o;
}

// ---------------- enc_term[b,j] = b_ih0[j]+b_hh0[j] + enc[b,:] . W_ih0[j, 512:1024] ----------------
__global__ __launch_bounds__(256) void k_encterm(const float* __restrict__ enc,
        const float* __restrict__ Wih0, const float* __restrict__ bih0,
        const float* __restrict__ bhh0, float* __restrict__ et) {
    int b = blockIdx.x >> 3, jc = blockIdx.x & 7;
    int tid = threadIdx.x, lane = tid & 63, w = tid >> 6;
    __shared__ float es[EE];
    if (tid < EE / 4) *(float4*)&es[tid * 4] = *(const float4*)&enc[b * EE + tid * 4];
    __syncthreads();
    float4 e0 = *(const float4*)&es[lane * 4];
    float4 e1 = *(const float4*)&es[256 + lane * 4];
    for (int o = 0; o < 64; ++o) {
        int j = jc * 256 + w * 64 + o;
        const float4* Wr = (const float4*)&Wih0[(size_t)j * (EE + DD) + DD];
        float4 w0 = Wr[lane], w1 = Wr[64 + lane];
        float s = w0.x*e0.x + w0.y*e0.y + w0.z*e0.z + w0.w*e0.w
                + w1.x*e1.x + w1.y*e1.y + w1.z*e1.z + w1.w*e1.w;
        #pragma unroll
        for (int off = 32; off; off >>= 1) s += __shfl_xor(s, off);
        if (lane == 0) et[b * G4 + j] = s + bih0[j] + bhh0[j];
    }
}

// ---------------- bf16 MFMA GEMM, C[M,N] = A[M,K] @ B[N,K]^T  (m97 structure) ----------------
template<int EPI>
__global__ __launch_bounds__(256) void k_gemm_bt(
        const unsigned short* __restrict__ A, const unsigned short* __restrict__ Bm,
        float* __restrict__ C, const float* __restrict__ extra,
        int M, int N, int K) {
    __shared__ __align__(16) unsigned short Alds[128 * 32];
    __shared__ __align__(16) unsigned short Blds[128 * 32];
    int tid = threadIdx.x, lane = tid & 63, w = tid >> 6;
    int wr = w >> 1, wc = w & 1;
    int m0 = blockIdx.x * 128, n0 = blockIdx.y * 128;
    f32x4 acc[4][4];
    #pragma unroll
    for (int i = 0; i < 4; i++)
        #pragma unroll
        for (int j = 0; j < 4; j++) acc[i][j] = (f32x4)0.f;

    const char* Abase = (const char*)A;
    const char* Bbase = (const char*)Bm;
    for (int ks = 0; ks < K; ks += 32) {
        #pragma unroll
        for (int c = 0; c < 2; ++c) {
            int f = (tid + c * 256) * 16;      // byte offset within 8KB tile
            int row = f >> 6;                  // 64 B per row (32 bf16)
            int inb = f & 63;
            const char* gA = Abase + (((size_t)(m0 + row) * K + ks) * 2 + inb);
            __builtin_amdgcn_global_load_lds(
                (const __attribute__((address_space(1))) void*)gA,
                (__attribute__((address_space(3))) void*)((char*)Alds + f), 16, 0, 0);
            const char* gB = Bbase + (((size_t)(n0 + row) * K + ks) * 2 + inb);
            __builtin_amdgcn_global_load_lds(
                (const __attribute__((address_space(1))) void*)gB,
                (__attribute__((address_space(3))) void*)((char*)Blds + f), 16, 0, 0);
        }
        __syncthreads();
        bf16x8 af[4], bfr[4];
        int r = lane & 15, ko = (lane >> 4) * 8;
        #pragma unroll
        for (int mi = 0; mi < 4; ++mi)
            af[mi] = *(const bf16x8*)&Alds[(wr * 64 + mi * 16 + r) * 32 + ko];
        #pragma unroll
        for (int ni = 0; ni < 4; ++ni)
            bfr[ni] = *(const bf16x8*)&Blds[(wc * 64 + ni * 16 + r) * 32 + ko];
        #pragma unroll
        for (int mi = 0; mi < 4; ++mi)
            #pragma unroll
            for (int ni = 0; ni < 4; ++ni)
                acc[mi][ni] = __builtin_amdgcn_mfma_f32_16x16x32_bf16(af[mi], bfr[ni], acc[mi][ni], 0, 0, 0);
        __syncthreads();
    }
    int cr = (lane >> 4) * 4, cc = lane & 15;
    #pragma unroll
    for (int mi = 0; mi < 4; ++mi) {
        #pragma unroll
        for (int ni = 0; ni < 4; ++ni) {
            int col = n0 + wc * 64 + ni * 16 + cc;
            #pragma unroll
            for (int rr = 0; rr < 4; ++rr) {
                int rowg = m0 + wr * 64 + mi * 16 + cr + rr;
                float v = acc[mi][ni][rr];
                if (EPI == 0) v += extra[(rowg >> 8) * G4 + col];
                else          v += extra[col];
                C[(size_t)rowg * N + col] = v;
            }
        }
    }
}

// ---------------- persistent dataflow recurrence ----------------
// 256 blocks x 64 threads. Blocks 0..127: layer 0 (d-slice of 4). Blocks 128..255: layer 1.
// Each block holds its 16-row MFMA B-tile (4 gates x 4 d) in fragment-ordered LDS (bf16).
// h0 history: h0hist[257][16][512] bf16 (slot 0 = zeros). h1 history = outsb[16][256][512].
// Per-step sync: release atomicAdd on flag[slot]; consumers spin with acquire loads.
__global__ __launch_bounds__(64) void k_recur(
        const float* __restrict__ Gx,
        const float* __restrict__ Whh0,
        const float* __restrict__ Wih1, const float* __restrict__ Whh1,
        const float* __restrict__ bih1, const float* __restrict__ bhh1,
        unsigned short* __restrict__ h0hist,
        unsigned short* __restrict__ outsb,
        const unsigned short* __restrict__ zbuf,
        int* __restrict__ flagH0, int* __restrict__ flagH1) {
    __shared__ __align__(16) unsigned short wfrag[32 * 512];   // [kt][lane][8] bf16
    __shared__ float scr[256];                                  // [16 b][16 col] gate exchange
    const int l = threadIdx.x;
    const int bid = blockIdx.x;
    const int role = bid >> 7;               // 0 = layer0, 1 = layer1
    const int d0 = (bid & 127) * 4;
    const int row16 = l & 15;                // fragment row this lane stages / output col
    const int jrow = (row16 >> 2) * 512 + d0 + (row16 & 3);   // gate-major j index
    const int ksub = (l >> 4) * 8;
    const int eb = l >> 2, ed = l & 3;       // elementwise mapping: (b, dj)

    // ---- stage weights into fragment-ordered LDS (once) ----
    const int nkt = role ? 32 : 16;
    for (int kt = 0; kt < nkt; ++kt) {
        const float* src;
        if (role == 0)    src = Whh0 + (size_t)jrow * DD + kt * 32 + ksub;
        else if (kt < 16) src = Wih1 + (size_t)jrow * DD + kt * 32 + ksub;
        else              src = Whh1 + (size_t)jrow * DD + (kt - 16) * 32 + ksub;
        float4 x = *(const float4*)src;
        float4 y = *(const float4*)(src + 4);
        bf16x8 w;
        w[0] = f2bf(x.x); w[1] = f2bf(x.y); w[2] = f2bf(x.z); w[3] = f2bf(x.w);
        w[4] = f2bf(y.x); w[5] = f2bf(y.y); w[6] = f2bf(y.z); w[7] = f2bf(y.w);
        *(bf16x8*)&wfrag[kt * 512 + l * 8] = w;
    }
    float binit = 0.f;
    if (role) binit = bih1[jrow] + bhh1[jrow];
    float cst = 0.f;                          // c-state for (eb, d0+ed), lives in a register
    __syncthreads();

    if (role == 0) {
        for (int t = 0; t < TT; ++t) {
            if (t > 0)
                while (__hip_atomic_load(flagH0 + t, __ATOMIC_ACQUIRE, __HIP_MEMORY_SCOPE_AGENT) < 128)
                    __builtin_amdgcn_s_sleep(1);
            const unsigned short* ab = h0hist + (size_t)t * (BB * DD) + row16 * DD + ksub;
            f32x4 acc = {0.f, 0.f, 0.f, 0.f};
            #pragma unroll
            for (int kt = 0; kt < 16; ++kt) {
                bf16x8 af = *(const bf16x8*)(ab + kt * 32);
                bf16x8 wf = *(const bf16x8*)&wfrag[kt * 512 + l * 8];
                acc = __builtin_amdgcn_mfma_f32_16x16x32_bf16(af, wf, acc, 0, 0, 0);
            }
            const int c = l & 15;
            const int jg = (c >> 2) * 512 + d0 + (c & 3);
            #pragma unroll
            for (int rr = 0; rr < 4; ++rr) {
                int b = (l >> 4) * 4 + rr;
                scr[b * 16 + c] = acc[rr] + Gx[((size_t)b * TT + t) * G4 + jg];
            }
            __syncthreads();
            float gi = scr[eb * 16 + ed],     gf = scr[eb * 16 + 4 + ed],
                  gg = scr[eb * 16 + 8 + ed], go = scr[eb * 16 + 12 + ed];
            float cn = sigmoidf_(gf) * cst + sigmoidf_(gi) * tanhf(gg);
            float hn = sigmoidf_(go) * tanhf(cn);
            cst = cn;
            h0hist[(size_t)(t + 1) * (BB * DD) + eb * DD + d0 + ed] = f2bf(hn);
            if (l == 0)
                __hip_atomic_fetch_add(flagH0 + t + 1, 1, __ATOMIC_RELEASE, __HIP_MEMORY_SCOPE_AGENT);
        }
    } else {
        for (int t = 0; t < TT; ++t) {
            while (__hip_atomic_load(flagH0 + t + 1, __ATOMIC_ACQUIRE, __HIP_MEMORY_SCOPE_AGENT) < 128)
                __builtin_amdgcn_s_sleep(1);
            if (t > 0)
                while (__hip_atomic_load(flagH1 + t, __ATOMIC_ACQUIRE, __HIP_MEMORY_SCOPE_AGENT) < 128)
                    __builtin_amdgcn_s_sleep(1);
            const unsigned short* xb = h0hist + (size_t)(t + 1) * (BB * DD) + row16 * DD + ksub;
            const unsigned short* hb = (t == 0)
                ? zbuf + row16 * DD + ksub
                : outsb + ((size_t)row16 * TT + (t - 1)) * DD + ksub;
            f32x4 acc = {binit, binit, binit, binit};
            #pragma unroll
            for (int kt = 0; kt < 16; ++kt) {
                bf16x8 af = *(const bf16x8*)(xb + kt * 32);
                bf16x8 wf = *(const bf16x8*)&wfrag[kt * 512 + l * 8];
                acc = __builtin_amdgcn_mfma_f32_16x16x32_bf16(af, wf, acc, 0, 0, 0);
            }
            #pragma unroll
            for (int kt = 0; kt < 16; ++kt) {
                bf16x8 af = *(const bf16x8*)(hb + kt * 32);
                bf16x8 wf = *(const bf16x8*)&wfrag[(16 + kt) * 512 + l * 8];
                acc = __builtin_amdgcn_mfma_f32_16x16x32_bf16(af, wf, acc, 0, 0, 0);
            }
            const int c = l & 15;
            #pragma unroll
            for (int rr = 0; rr < 4; ++rr) {
                int b = (l >> 4) * 4 + rr;
                scr[b * 16 + c] = acc[rr];
            }
            __syncthreads();
            float gi = scr[eb * 16 + ed],     gf = scr[eb * 16 + 4 + ed],
                  gg = scr[eb * 16 + 8 + ed], go = scr[eb * 16 + 12 + ed];
            float cn = sigmoidf_(gf) * cst + sigmoidf_(gi) * tanhf(gg);
            float hn = sigmoidf_(go) * tanhf(cn);
            cst = cn;
            outsb[((size_t)eb * TT + t) * DD + d0 + ed] = f2bf(hn);
            if (l == 0)
                __hip_atomic_fetch_add(flagH1 + t + 1, 1, __ATOMIC_RELEASE, __HIP_MEMORY_SCOPE_AGENT);
        }
    }
}

extern "C" void kernel_launch(void* const* d_in, const int* in_sizes, int n_in,
                              void* d_out, int out_size, void* d_ws, size_t ws_size,
                              hipStream_t stream) {
    const int*   tok   = (const int*)  d_in[0];
    const float* enc   = (const float*)d_in[1];
    const float* embed = (const float*)d_in[2];
    const float* Wih0  = (const float*)d_in[3];
    const float* Whh0  = (const float*)d_in[4];
    const float* bih0  = (const float*)d_in[5];
    const float* bhh0  = (const float*)d_in[6];
    const float* Wih1  = (const float*)d_in[7];
    const float* Whh1  = (const float*)d_in[8];
    const float* bih1  = (const float*)d_in[9];
    const float* bhh1  = (const float*)d_in[10];
    const float* Wout  = (const float*)d_in[11];
    const float* bout  = (const float*)d_in[12];
    float* out = (float*)d_out;

    char* ws = (char*)d_ws;
    size_t off = 0;
    auto alloc = [&](size_t bytes) -> char* {
        char* p = ws + off; off += (bytes + 255) & ~(size_t)255; return p;
    };
    unsigned short* Xb     = (unsigned short*)alloc((size_t)BB * TT * DD * 2);
    unsigned short* Wih0xb = (unsigned short*)alloc((size_t)G4 * DD * 2);
    unsigned short* Woutb  = (unsigned short*)alloc((size_t)VV * DD * 2);
    float*          et     = (float*)alloc((size_t)BB * G4 * sizeof(float));
    float*          Gx     = (float*)alloc((size_t)BB * TT * G4 * sizeof(float));
    unsigned short* outsb  = (unsigned short*)alloc((size_t)BB * TT * DD * 2);
    unsigned short* h0hist = (unsigned short*)alloc((size_t)(TT + 1) * BB * DD * 2);
    unsigned short* zbuf   = (unsigned short*)alloc((size_t)BB * DD * 2);
    int*            flags  = (int*)alloc(2 * 300 * sizeof(int));
    int* flagH0 = flags;
    int* flagH1 = flags + 300;

    hipMemsetAsync(h0hist, 0, (size_t)BB * DD * 2, stream);   // slot 0 = zeros
    hipMemsetAsync(zbuf, 0, (size_t)BB * DD * 2, stream);
    hipMemsetAsync(flags, 0, 2 * 300 * sizeof(int), stream);

    k_gather<<<BB * TT, 256, 0, stream>>>(tok, embed, Xb);
    k_cvt<<<(VV * DD / 4 + 255) / 256, 256, 0, stream>>>(Wout, Woutb, VV * DD / 4);
    k_cvt_wih0x<<<(G4 * DD / 4) / 256, 256, 0, stream>>>(Wih0, Wih0xb);
    k_encterm<<<BB * 8, 256, 0, stream>>>(enc, Wih0, bih0, bhh0, et);

    dim3 g1(BB * TT / 128, G4 / 128);
    k_gemm_bt<0><<<g1, 256, 0, stream>>>(Xb, Wih0xb, Gx, et, BB * TT, G4, DD);

    k_recur<<<256, 64, 0, stream>>>(Gx, Whh0, Wih1, Whh1, bih1, bhh1,
                                    h0hist, outsb, zbuf, flagH0, flagH1);

    dim3 g2(BB * TT / 128, VV / 128);
    k_gemm_bt<1><<<g2, 256, 0, stream>>>(outsb, Woutb, out, bout, BB * TT, VV, DD);
}

// Round 3
// 1855.841 us; speedup vs baseline: 7.4776x; 1.6818x over previous
//
#include <hip/hip_runtime.h>
#include <hip/hip_bf16.h>
#include <math.h>

#define BB 16
#define TT 256
#define DD 512
#define EE 512
#define VV 32000
#define G4 2048   // 4*D

typedef __attribute__((ext_vector_type(4))) float f32x4;
typedef __attribute__((ext_vector_type(8))) short bf16x8;

union frag_u { unsigned long long u[2]; bf16x8 v; };

#define SENTMASK 0x4000400040004000ULL   // bit14 of each bf16: set in 0xFFFF sentinel, clear for |x|<2

__device__ __forceinline__ unsigned short f2bf(float x) {
    unsigned u = __float_as_uint(x);
    unsigned r = (u + 0x7FFFu + ((u >> 16) & 1u)) >> 16;
    return (unsigned short)r;
}

__device__ __forceinline__ float sigmoidf_(float x) { return 1.0f / (1.0f + expf(-x)); }

// ---------------- embedding gather -> bf16 (padding_idx=0 -> zero row) ----------------
__global__ __launch_bounds__(256) void k_gather(const int* __restrict__ tok,
        const float* __restrict__ embed, unsigned short* __restrict__ Xb) {
    int m = blockIdx.x;
    int tk = tok[m];
    const float* src = embed + (size_t)tk * DD;
    int i = threadIdx.x * 2;
    float vx = 0.f, vy = 0.f;
    if (tk != 0) { float2 v = *(const float2*)&src[i]; vx = v.x; vy = v.y; }
    ushort2 o; o.x = f2bf(vx); o.y = f2bf(vy);
    *(ushort2*)&Xb[(size_t)m * DD + i] = o;
}

// ---------------- generic fp32 -> bf16 convert (contiguous) ----------------
__global__ __launch_bounds__(256) void k_cvt(const float* __restrict__ in,
        unsigned short* __restrict__ out, int n4) {
    int i = blockIdx.x * 256 + threadIdx.x;
    if (i >= n4) return;
    float4 v = ((const float4*)in)[i];
    ushort4 o; o.x = f2bf(v.x); o.y = f2bf(v.y); o.z = f2bf(v.z); o.w = f2bf(v.w);
    ((ushort4*)out)[i] = o;
}

// ---------------- W_ih0[:, 0:512] -> packed bf16 [2048,512] ----------------
__global__ __launch_bounds__(256) void k_cvt_wih0x(const float* __restrict__ Wih0,
        unsigned short* __restrict__ out) {
    int i = blockIdx.x * 256 + threadIdx.x;
    int j = i >> 7;
    int k4 = (i & 127) << 2;
    float4 v = *(const float4*)&Wih0[(size_t)j * (EE + DD) + k4];
    ushort4 o; o.x = f2bf(v.x); o.y = f2bf(v.y); o.z = f2bf(v.z); o.w = f2bf(v.w);
    *(ushort4*)&out[(size_t)j * DD + k4] = o;
}

// ---------------- enc_term[b,j] = b_ih0[j]+b_hh0[j] + enc[b,:] . W_ih0[j, 512:1024] ----------------
__global__ __launch_bounds__(256) void k_encterm(const float* __restrict__ enc,
        const float* __restrict__ Wih0, const float* __restrict__ bih0,
        const float* __restrict__ bhh0, float* __restrict__ et) {
    int b = blockIdx.x >> 3, jc = blockIdx.x & 7;
    int tid = threadIdx.x, lane = tid & 63, w = tid >> 6;
    __shared__ float es[EE];
    if (tid < EE / 4) *(float4*)&es[tid * 4] = *(const float4*)&enc[b * EE + tid * 4];
    __syncthreads();
    float4 e0 = *(const float4*)&es[lane * 4];
    float4 e1 = *(const float4*)&es[256 + lane * 4];
    for (int o = 0; o < 64; ++o) {
        int j = jc * 256 + w * 64 + o;
        const float4* Wr = (const float4*)&Wih0[(size_t)j * (EE + DD) + DD];
        float4 w0 = Wr[lane], w1 = Wr[64 + lane];
        float s = w0.x*e0.x + w0.y*e0.y + w0.z*e0.z + w0.w*e0.w
                + w1.x*e1.x + w1.y*e1.y + w1.z*e1.z + w1.w*e1.w;
        #pragma unroll
        for (int off = 32; off; off >>= 1) s += __shfl_xor(s, off);
        if (lane == 0) et[b * G4 + j] = s + bih0[j] + bhh0[j];
    }
}

// ---------------- bf16 MFMA GEMM, C[M,N] = A[M,K] @ B[N,K]^T  (m97 structure) ----------------
template<int EPI>
__global__ __launch_bounds__(256) void k_gemm_bt(
        const unsigned short* __restrict__ A, const unsigned short* __restrict__ Bm,
        float* __restrict__ C, const float* __restrict__ extra,
        int M, int N, int K) {
    __shared__ __align__(16) unsigned short Alds[128 * 32];
    __shared__ __align__(16) unsigned short Blds[128 * 32];
    int tid = threadIdx.x, lane = tid & 63, w = tid >> 6;
    int wr = w >> 1, wc = w & 1;
    int m0 = blockIdx.x * 128, n0 = blockIdx.y * 128;
    f32x4 acc[4][4];
    #pragma unroll
    for (int i = 0; i < 4; i++)
        #pragma unroll
        for (int j = 0; j < 4; j++) acc[i][j] = (f32x4)0.f;

    const char* Abase = (const char*)A;
    const char* Bbase = (const char*)Bm;
    for (int ks = 0; ks < K; ks += 32) {
        #pragma unroll
        for (int c = 0; c < 2; ++c) {
            int f = (tid + c * 256) * 16;
            int row = f >> 6;
            int inb = f & 63;
            const char* gA = Abase + (((size_t)(m0 + row) * K + ks) * 2 + inb);
            __builtin_amdgcn_global_load_lds(
                (const __attribute__((address_space(1))) void*)gA,
                (__attribute__((address_space(3))) void*)((char*)Alds + f), 16, 0, 0);
            const char* gB = Bbase + (((size_t)(n0 + row) * K + ks) * 2 + inb);
            __builtin_amdgcn_global_load_lds(
                (const __attribute__((address_space(1))) void*)gB,
                (__attribute__((address_space(3))) void*)((char*)Blds + f), 16, 0, 0);
        }
        __syncthreads();
        bf16x8 af[4], bfr[4];
        int r = lane & 15, ko = (lane >> 4) * 8;
        #pragma unroll
        for (int mi = 0; mi < 4; ++mi)
            af[mi] = *(const bf16x8*)&Alds[(wr * 64 + mi * 16 + r) * 32 + ko];
        #pragma unroll
        for (int ni = 0; ni < 4; ++ni)
            bfr[ni] = *(const bf16x8*)&Blds[(wc * 64 + ni * 16 + r) * 32 + ko];
        #pragma unroll
        for (int mi = 0; mi < 4; ++mi)
            #pragma unroll
            for (int ni = 0; ni < 4; ++ni)
                acc[mi][ni] = __builtin_amdgcn_mfma_f32_16x16x32_bf16(af[mi], bfr[ni], acc[mi][ni], 0, 0, 0);
        __syncthreads();
    }
    int cr = (lane >> 4) * 4, cc = lane & 15;
    #pragma unroll
    for (int mi = 0; mi < 4; ++mi) {
        #pragma unroll
        for (int ni = 0; ni < 4; ++ni) {
            int col = n0 + wc * 64 + ni * 16 + cc;
            #pragma unroll
            for (int rr = 0; rr < 4; ++rr) {
                int rowg = m0 + wr * 64 + mi * 16 + cr + rr;
                float v = acc[mi][ni][rr];
                if (EPI == 0) v += extra[(rowg >> 8) * G4 + col];
                else          v += extra[col];
                C[(size_t)rowg * N + col] = v;
            }
        }
    }
}

// ---------------- poll helper: load 16 MFMA A-fragments, retry until no sentinel ----------------
__device__ __forceinline__ void poll16(const unsigned long long* row, int q,
        unsigned long long* ax, unsigned long long* ay) {
    for (;;) {
        unsigned long long bad = 0;
        #pragma unroll
        for (int kt = 0; kt < 16; ++kt) {
            ax[kt] = __hip_atomic_load(row + kt * 8 + q * 2,
                                       __ATOMIC_RELAXED, __HIP_MEMORY_SCOPE_AGENT);
            ay[kt] = __hip_atomic_load(row + kt * 8 + q * 2 + 1,
                                       __ATOMIC_RELAXED, __HIP_MEMORY_SCOPE_AGENT);
            bad |= (ax[kt] | ay[kt]) & SENTMASK;
        }
        if (!__any(bad != 0)) break;
        __builtin_amdgcn_s_sleep(0);
    }
}

// ---------------- persistent dataflow recurrence (fence-free sentinel sync) ----------------
// 64 blocks x 64 threads. Blocks 0..31: layer 0, d-slice of 16; blocks 32..63: layer 1.
// wfrag LDS [4 gate-tiles][32 kt][lane*8] bf16 = 128 KB. All cross-block h traffic via
// relaxed agent-scope atomics (sc1: bypass non-coherent L2). Validity = bit14 clear.
__global__ __launch_bounds__(64) void k_recur(
        const float* __restrict__ Gx,
        const float* __restrict__ Whh0,
        const float* __restrict__ Wih1, const float* __restrict__ Whh1,
        const float* __restrict__ bih1, const float* __restrict__ bhh1,
        unsigned short* h0hist, unsigned short* outsb,
        const unsigned short* zbuf) {
    __shared__ __align__(16) unsigned short wfrag[4 * 32 * 512];   // 128 KB
    const int l = threadIdx.x;
    const int bid = blockIdx.x;
    const int role = bid >> 5;
    const int d0 = (bid & 31) * 16;
    const int r16 = l & 15;           // B-row within tile / A b-row / output col
    const int q = l >> 4;             // k-quadrant
    const int ksub = q * 8;
    const int b0 = q * 4;             // output b base (C/D: row=(lane>>4)*4+reg)

    // ---- stage weights into fragment-ordered LDS (once) ----
    const int nkt = role ? 32 : 16;
    for (int tile = 0; tile < 4; ++tile) {
        int j = tile * 512 + d0 + r16;            // gate=tile, dim=d0+r16
        for (int kt = 0; kt < nkt; ++kt) {
            const float* src;
            if (role == 0)    src = Whh0 + (size_t)j * DD + kt * 32 + ksub;
            else if (kt < 16) src = Wih1 + (size_t)j * DD + kt * 32 + ksub;
            else              src = Whh1 + (size_t)j * DD + (kt - 16) * 32 + ksub;
            float4 x = *(const float4*)src;
            float4 y = *(const float4*)(src + 4);
            bf16x8 w;
            w[0] = f2bf(x.x); w[1] = f2bf(x.y); w[2] = f2bf(x.z); w[3] = f2bf(x.w);
            w[4] = f2bf(y.x); w[5] = f2bf(y.y); w[6] = f2bf(y.z); w[7] = f2bf(y.w);
            *(bf16x8*)&wfrag[((tile * 32 + kt) * 64 + l) * 8] = w;
        }
    }
    __syncthreads();

    float cst[4] = {0.f, 0.f, 0.f, 0.f};
    unsigned long long ax[16], ay[16];

    if (role == 0) {
        for (int t = 0; t < TT; ++t) {
            // Gx prefetch (independent of h -> issues before/under the poll)
            float gx[4][4];
            #pragma unroll
            for (int ni = 0; ni < 4; ++ni)
                #pragma unroll
                for (int rr = 0; rr < 4; ++rr)
                    gx[ni][rr] = Gx[((size_t)(b0 + rr) * TT + t) * G4 + ni * 512 + d0 + r16];

            const unsigned long long* hrow =
                (const unsigned long long*)(h0hist + (size_t)t * (BB * DD) + r16 * DD);
            poll16(hrow, q, ax, ay);

            f32x4 acc[4];
            #pragma unroll
            for (int ni = 0; ni < 4; ++ni) acc[ni] = (f32x4)0.f;
            #pragma unroll
            for (int kt = 0; kt < 16; ++kt) {
                frag_u f; f.u[0] = ax[kt]; f.u[1] = ay[kt];
                #pragma unroll
                for (int ni = 0; ni < 4; ++ni) {
                    bf16x8 wf = *(const bf16x8*)&wfrag[((ni * 32 + kt) * 64 + l) * 8];
                    acc[ni] = __builtin_amdgcn_mfma_f32_16x16x32_bf16(f.v, wf, acc[ni], 0, 0, 0);
                }
            }
            unsigned short* orow = h0hist + (size_t)(t + 1) * (BB * DD);
            #pragma unroll
            for (int rr = 0; rr < 4; ++rr) {
                float gi = acc[0][rr] + gx[0][rr], gf = acc[1][rr] + gx[1][rr];
                float gg = acc[2][rr] + gx[2][rr], go = acc[3][rr] + gx[3][rr];
                float cn = sigmoidf_(gf) * cst[rr] + sigmoidf_(gi) * tanhf(gg);
                float hn = sigmoidf_(go) * tanhf(cn);
                cst[rr] = cn;
                __hip_atomic_store(orow + (b0 + rr) * DD + d0 + r16, f2bf(hn),
                                   __ATOMIC_RELAXED, __HIP_MEMORY_SCOPE_AGENT);
            }
        }
    } else {
        float bin[4];
        #pragma unroll
        for (int ni = 0; ni < 4; ++ni)
            bin[ni] = bih1[ni * 512 + d0 + r16] + bhh1[ni * 512 + d0 + r16];
        for (int t = 0; t < TT; ++t) {
            // x = h0[t] (slot t+1)
            const unsigned long long* xrow =
                (const unsigned long long*)(h0hist + (size_t)(t + 1) * (BB * DD) + r16 * DD);
            poll16(xrow, q, ax, ay);

            f32x4 acc[4];
            #pragma unroll
            for (int ni = 0; ni < 4; ++ni)
                acc[ni] = (f32x4){bin[ni], bin[ni], bin[ni], bin[ni]};
            #pragma unroll
            for (int kt = 0; kt < 16; ++kt) {
                frag_u f; f.u[0] = ax[kt]; f.u[1] = ay[kt];
                #pragma unroll
                for (int ni = 0; ni < 4; ++ni) {
                    bf16x8 wf = *(const bf16x8*)&wfrag[((ni * 32 + kt) * 64 + l) * 8];
                    acc[ni] = __builtin_amdgcn_mfma_f32_16x16x32_bf16(f.v, wf, acc[ni], 0, 0, 0);
                }
            }
            // h1[t-1]
            const unsigned long long* hrow = (t == 0)
                ? (const unsigned long long*)(zbuf + r16 * DD)
                : (const unsigned long long*)(outsb + ((size_t)r16 * TT + (t - 1)) * DD);
            poll16(hrow, q, ax, ay);
            #pragma unroll
            for (int kt = 0; kt < 16; ++kt) {
                frag_u f; f.u[0] = ax[kt]; f.u[1] = ay[kt];
                #pragma unroll
                for (int ni = 0; ni < 4; ++ni) {
                    bf16x8 wf = *(const bf16x8*)&wfrag[((ni * 32 + 16 + kt) * 64 + l) * 8];
                    acc[ni] = __builtin_amdgcn_mfma_f32_16x16x32_bf16(f.v, wf, acc[ni], 0, 0, 0);
                }
            }
            #pragma unroll
            for (int rr = 0; rr < 4; ++rr) {
                float gi = acc[0][rr], gf = acc[1][rr], gg = acc[2][rr], go = acc[3][rr];
                float cn = sigmoidf_(gf) * cst[rr] + sigmoidf_(gi) * tanhf(gg);
                float hn = sigmoidf_(go) * tanhf(cn);
                cst[rr] = cn;
                __hip_atomic_store(outsb + ((size_t)(b0 + rr) * TT + t) * DD + d0 + r16, f2bf(hn),
                                   __ATOMIC_RELAXED, __HIP_MEMORY_SCOPE_AGENT);
            }
        }
    }
}

extern "C" void kernel_launch(void* const* d_in, const int* in_sizes, int n_in,
                              void* d_out, int out_size, void* d_ws, size_t ws_size,
                              hipStream_t stream) {
    const int*   tok   = (const int*)  d_in[0];
    const float* enc   = (const float*)d_in[1];
    const float* embed = (const float*)d_in[2];
    const float* Wih0  = (const float*)d_in[3];
    const float* Whh0  = (const float*)d_in[4];
    const float* bih0  = (const float*)d_in[5];
    const float* bhh0  = (const float*)d_in[6];
    const float* Wih1  = (const float*)d_in[7];
    const float* Whh1  = (const float*)d_in[8];
    const float* bih1  = (const float*)d_in[9];
    const float* bhh1  = (const float*)d_in[10];
    const float* Wout  = (const float*)d_in[11];
    const float* bout  = (const float*)d_in[12];
    float* out = (float*)d_out;

    char* ws = (char*)d_ws;
    size_t off = 0;
    auto alloc = [&](size_t bytes) -> char* {
        char* p = ws + off; off += (bytes + 255) & ~(size_t)255; return p;
    };
    unsigned short* Xb     = (unsigned short*)alloc((size_t)BB * TT * DD * 2);
    unsigned short* Wih0xb = (unsigned short*)alloc((size_t)G4 * DD * 2);
    unsigned short* Woutb  = (unsigned short*)alloc((size_t)VV * DD * 2);
    float*          et     = (float*)alloc((size_t)BB * G4 * sizeof(float));
    float*          Gx     = (float*)alloc((size_t)BB * TT * G4 * sizeof(float));
    unsigned short* outsb  = (unsigned short*)alloc((size_t)BB * TT * DD * 2);
    unsigned short* h0hist = (unsigned short*)alloc((size_t)(TT + 1) * BB * DD * 2);
    unsigned short* zbuf   = (unsigned short*)alloc((size_t)BB * DD * 2);

    // sentinel init: slot 0 of h0hist + zbuf = zeros (valid), everything else 0xFF (invalid)
    hipMemsetAsync(h0hist, 0, (size_t)BB * DD * 2, stream);
    hipMemsetAsync(h0hist + (size_t)BB * DD, 0xFF, (size_t)TT * BB * DD * 2, stream);
    hipMemsetAsync(outsb, 0xFF, (size_t)BB * TT * DD * 2, stream);
    hipMemsetAsync(zbuf, 0, (size_t)BB * DD * 2, stream);

    k_gather<<<BB * TT, 256, 0, stream>>>(tok, embed, Xb);
    k_cvt<<<(VV * DD / 4 + 255) / 256, 256, 0, stream>>>(Wout, Woutb, VV * DD / 4);
    k_cvt_wih0x<<<(G4 * DD / 4) / 256, 256, 0, stream>>>(Wih0, Wih0xb);
    k_encterm<<<BB * 8, 256, 0, stream>>>(enc, Wih0, bih0, bhh0, et);

    dim3 g1(BB * TT / 128, G4 / 128);
    k_gemm_bt<0><<<g1, 256, 0, stream>>>(Xb, Wih0xb, Gx, et, BB * TT, G4, DD);

    k_recur<<<64, 64, 0, stream>>>(Gx, Whh0, Wih1, Whh1, bih1, bhh1,
                                   h0hist, outsb, zbuf);

    dim3 g2(BB * TT / 128, VV / 128);
    k_gemm_bt<1><<<g2, 256, 0, stream>>>(outsb, Woutb, out, bout, BB * TT, VV, DD);
}